// Round 8
// baseline (172.297 us; speedup 1.0000x reference)
//
#include <hip/hip_runtime.h>

// All I/O is float32 (established round 7). Fixed ~78us harness restore
// overhead is untouchable; kernel time is the optimization target.

#define L_    1024
#define C_    16
#define US_   32
#define HID_  128
#define TI1   8
#define TI2   8
#define K2    2.885390082f   // 2*log2(e): e^{2x} = 2^{K2*x}

__device__ __forceinline__ float frcp(float x)  { return __builtin_amdgcn_rcpf(x); }
__device__ __forceinline__ float fexp2(float x) { return __builtin_amdgcn_exp2f(x); }

struct BranchP {
  const float *x, *Wt, *Wx, *bh, *Wa, *ba, *g1, *be1, *W1, *b1, *W2, *b2, *g2, *be2;
  float* y;   // out: [4][1024][16] fp32, position-major
};

// One block: (branch, batch, 8-row i-tile). Self-attn(band) + LN + FF + LN.
// 32 lanes per row (lanes of one wave half); cross-lane combine via shfl_xor 16.
__global__ __launch_bounds__(256) void branch_kernel(BranchP Pa, BranchP Pb) {
  const BranchP P = blockIdx.z ? Pb : Pa;
  const int b   = blockIdx.y;
  const int i0  = blockIdx.x * TI1;
  const int tid = threadIdx.x;
  const int j0  = max(0, i0 - 63);
  const int j1  = min(L_, i0 + TI1 + 64);
  const int Wd  = j1 - j0;               // <= 135

  __shared__ float xs[C_][137];          // x[c][j-j0]
  __shared__ union {
    struct { float ks[136][33]; float qs[TI1][33]; } a;                       // P1-P2
    struct { float W1s[C_][129]; float W2s[HID_][17]; float b1s[HID_]; } bb;  // P3+
  } ovl;
  __shared__ float es[TI1][129];
  __shared__ float ya[TI1][17];
  __shared__ float Wts[C_][US_], Wxs[C_][US_];   // pre-scaled by K2
  __shared__ float m2was[US_], bhs[US_];         // -2*Wa ; K2*bh
  __shared__ float g1s[C_], be1s[C_], b2s[C_], g2s[C_], be2s[C_];
  __shared__ float bas;

  // ---- register prefetch of FF weights (consumed at P3) ----
  float w1r[8], w2r[8], b1r = 0.f;
#pragma unroll
  for (int t = 0; t < 8; ++t) { w1r[t] = P.W1[tid + 256 * t]; w2r[t] = P.W2[tid + 256 * t]; }
  if (tid < HID_) b1r = P.b1[tid];

  // ---- P0: weights + x slice ----
  for (int idx = tid; idx < C_ * US_; idx += 256) {
    int c = idx >> 5, u = idx & 31;
    Wts[c][u] = K2 * P.Wt[idx];
    Wxs[c][u] = K2 * P.Wx[idx];
  }
  if (tid < US_) { m2was[tid] = -2.0f * P.Wa[tid]; bhs[tid] = K2 * P.bh[tid]; }
  if (tid < C_) {
    g1s[tid] = P.g1[tid]; be1s[tid] = P.be1[tid];
    g2s[tid] = P.g2[tid]; be2s[tid] = P.be2[tid];
    b2s[tid] = P.b2[tid];
  }
  if (tid == 0) bas = P.ba[0];
  for (int idx = tid; idx < C_ * Wd; idx += 256) {
    int c = idx / Wd, jj = idx - c * Wd;
    xs[c][jj] = P.x[(b * C_ + c) * L_ + j0 + jj];
  }
  __syncthreads();

  // ---- P1: k = K2*(x@Wx + bh), q = K2*(x@Wt) ----
  for (int idx = tid; idx < Wd * US_; idx += 256) {
    int j = idx >> 5, u = idx & 31;
    float a = bhs[u];
#pragma unroll
    for (int c = 0; c < C_; ++c) a = fmaf(xs[c][j], Wxs[c][u], a);
    ovl.a.ks[j][u] = a;
  }
  {
    int i = tid >> 5, u = tid & 31;    // exactly 256 = 8*32
    float a = 0.f;
#pragma unroll
    for (int c = 0; c < C_; ++c) a = fmaf(xs[c][i0 - j0 + i], Wts[c][u], a);
    ovl.a.qs[i][u] = a;
  }
  __syncthreads();

  const int il   = tid >> 5;            // row 0..7
  const int sub  = tid & 31;            // 32 lanes per row
  const int ig   = i0 + il;
  const int jlo  = max(0, ig - 63), jhi = min(L_, ig + 65);
  const int nj   = jhi - jlo;           // 64..128
  const int jb   = jlo - j0;
  const int c16  = sub & 15;            // channel for 16-wide phases
  const int half = sub >> 4;            // 0/1 split of the 32 lanes

  // ---- P2: e = ba + sum_u Wa[u]*tanh(.) ; tanh = 1 - 2/(1+2^z) ----
  float inv;
  {
    float xq[US_];
#pragma unroll
    for (int u = 0; u < US_; ++u) xq[u] = ovl.a.qs[il][u];
    float eacc = bas;
#pragma unroll
    for (int u = 0; u < US_; ++u) eacc -= 0.5f * m2was[u];   // ba + sum(Wa)
    float mx = -1e30f;
    for (int jj = sub; jj < nj; jj += 32) {
      const float* kr = ovl.a.ks[jb + jj];
      float acc = eacc;
#pragma unroll
      for (int u = 0; u < US_; ++u) {
        float t = fexp2(xq[u] + kr[u]);
        acc = fmaf(m2was[u], frcp(1.0f + t), acc);
      }
      es[il][jj] = acc;
      mx = fmaxf(mx, acc);
    }
#pragma unroll
    for (int m = 16; m; m >>= 1) mx = fmaxf(mx, __shfl_xor(mx, m));
    float s = 0.f;
    for (int jj = sub; jj < nj; jj += 32) {
      float v = __expf(es[il][jj] - mx);
      es[il][jj] = v; s += v;
    }
#pragma unroll
    for (int m = 16; m; m >>= 1) s += __shfl_xor(s, m);
    inv = frcp(s + 1e-5f);
  }
  __syncthreads();

  // ---- P3: FF weights regs->LDS (dead union); v = a@x ; residual ; LN1 ----
#pragma unroll
  for (int t = 0; t < 8; ++t) {
    int idx = tid + 256 * t;
    ovl.bb.W1s[idx >> 7][idx & 127] = w1r[t];
  }
#pragma unroll
  for (int t = 0; t < 8; ++t) {
    int idx = tid + 256 * t;
    ovl.bb.W2s[idx >> 4][idx & 15] = w2r[t];
  }
  if (tid < HID_) ovl.bb.b1s[tid] = b1r;
  float yln;
  {
    float v = 0.f;
    for (int jj = half; jj < nj; jj += 2) v = fmaf(es[il][jj], xs[c16][jb + jj], v);
    v += __shfl_xor(v, 16);
    float y0 = xs[c16][ig - j0] + v * inv;
    float s1 = y0, s2 = y0 * y0;
#pragma unroll
    for (int m = 8; m; m >>= 1) { s1 += __shfl_xor(s1, m); s2 += __shfl_xor(s2, m); }
    float mean = s1 * (1.f / 16.f);
    float var  = s2 * (1.f / 16.f) - mean * mean;
    float rstd = rsqrtf(fmaxf(var, 0.f) + 1e-14f);
    yln = (y0 - mean) * rstd * g1s[c16] + be1s[c16];
    if (half == 0) ya[il][c16] = yln;
  }
  __syncthreads();

  // ---- P4: h = relu(y@W1 + b1) ----
#pragma unroll
  for (int t = 0; t < 4; ++t) {
    int u = sub + 32 * t;
    float a = ovl.bb.b1s[u];
#pragma unroll
    for (int c = 0; c < C_; ++c) a = fmaf(ya[il][c], ovl.bb.W1s[c][u], a);
    es[il][u] = fmaxf(a, 0.f);
  }
  __syncthreads();

  // ---- P5: FF out + residual + LN2 -> fp32 y [b][i][c] ----
  {
    float o = 0.f;
    int u0 = half * 64;
#pragma unroll
    for (int uu = 0; uu < 64; ++uu) o = fmaf(es[il][u0 + uu], ovl.bb.W2s[u0 + uu][c16], o);
    o += __shfl_xor(o, 16);
    float y0 = yln + o + b2s[c16];
    float s1 = y0, s2 = y0 * y0;
#pragma unroll
    for (int m = 8; m; m >>= 1) { s1 += __shfl_xor(s1, m); s2 += __shfl_xor(s2, m); }
    float mean = s1 * (1.f / 16.f);
    float var  = s2 * (1.f / 16.f) - mean * mean;
    float rstd = rsqrtf(fmaxf(var, 0.f) + 1e-14f);
    if (half == 0)
      P.y[(b * L_ + ig) * C_ + c16] = (y0 - mean) * rstd * g2s[c16] + be2s[c16];
  }
}

// Cross-attn via M = Wq*Wk^T fusion: score = y1^T M y2 ; out = (a@y2^T)@Wv.
__global__ __launch_bounds__(256) void cross_kernel(
    const float* __restrict__ y1g, const float* __restrict__ y2g,
    const float* Wq, const float* Wk, const float* Wv,
    const float* g1, const float* be1, const float* W1, const float* b1,
    const float* W2, const float* b2, const float* g2, const float* be2,
    float* out) {
  const int b   = blockIdx.y;
  const int i0  = blockIdx.x * TI2;
  const int tid = threadIdx.x;
  const int j0  = max(0, i0 - 63);
  const int j1  = min(L_, i0 + TI2 + 64);
  const int Wd  = j1 - j0;               // <= 135

  __shared__ float y1s[TI2][17];
  __shared__ float y2s[136][17];
  __shared__ float Ms[C_][17];
  __shared__ float zs[TI2][17];          // z; reused as wv; reused as final out
  __shared__ float es[TI2][129];
  __shared__ float ya[TI2][17];
  __shared__ float Wqs[C_][C_], Wks[C_][C_], Wvs[C_][C_];
  __shared__ float W1s[C_][129], W2s[HID_][17], b1s[HID_];
  __shared__ float g1s[C_], be1s[C_], b2s[C_], g2s[C_], be2s[C_];

  // ---- P0 ----
  {
    int c = tid >> 4, u = tid & 15;
    Wqs[c][u] = Wq[tid]; Wks[c][u] = Wk[tid]; Wvs[c][u] = Wv[tid];
  }
  if (tid < TI2 * C_)
    y1s[tid >> 4][tid & 15] = y1g[(b * L_ + i0 + (tid >> 4)) * C_ + (tid & 15)];
  for (int idx = tid; idx < C_ * HID_; idx += 256) {
    W1s[idx >> 7][idx & 127] = W1[idx];
    W2s[idx >> 4][idx & 15]  = W2[idx];
  }
  if (tid < HID_) b1s[tid] = b1[tid];
  if (tid < C_) {
    g1s[tid] = g1[tid]; be1s[tid] = be1[tid];
    g2s[tid] = g2[tid]; be2s[tid] = be2[tid];
    b2s[tid] = b2[tid];
  }
  for (int idx = tid; idx < Wd * C_; idx += 256) {
    int jj = idx >> 4, c = idx & 15;
    y2s[jj][c] = y2g[(b * L_ + j0 + jj) * C_ + c];
  }
  __syncthreads();

  // ---- P1a: M = 0.25 * Wq Wk^T ----
  {
    int c1 = tid >> 4, c2 = tid & 15;
    float m = 0.f;
#pragma unroll
    for (int u = 0; u < C_; ++u) m = fmaf(Wqs[c1][u], Wks[c2][u], m);
    Ms[c1][c2] = 0.25f * m;
  }
  __syncthreads();
  // ---- P1b: z[i][c] = sum_c' y1[i][c'] M[c'][c] ----
  if (tid < TI2 * C_) {
    int i = tid >> 4, c = tid & 15;
    float z = 0.f;
#pragma unroll
    for (int cc = 0; cc < C_; ++cc) z = fmaf(y1s[i][cc], Ms[cc][c], z);
    zs[i][c] = z;
  }
  __syncthreads();

  const int il   = tid >> 5;            // row 0..7
  const int sub  = tid & 31;
  const int ig   = i0 + il;
  const int jlo  = max(0, ig - 63), jhi = min(L_, ig + 65);
  const int nj   = jhi - jlo;
  const int jb   = jlo - j0;
  const int c16  = sub & 15;
  const int half = sub >> 4;

  // ---- P2: scores + exact softmax ----
  float inv;
  {
    float zr[C_];
#pragma unroll
    for (int c = 0; c < C_; ++c) zr[c] = zs[il][c];
    float mx = -1e30f;
    for (int jj = sub; jj < nj; jj += 32) {
      const float* yr = y2s[jb + jj];
      float a = 0.f;
#pragma unroll
      for (int c = 0; c < C_; ++c) a = fmaf(zr[c], yr[c], a);
      es[il][jj] = a;
      mx = fmaxf(mx, a);
    }
#pragma unroll
    for (int m = 16; m; m >>= 1) mx = fmaxf(mx, __shfl_xor(mx, m));
    float s = 0.f;
    for (int jj = sub; jj < nj; jj += 32) {
      float v = __expf(es[il][jj] - mx);
      es[il][jj] = v; s += v;
    }
#pragma unroll
    for (int m = 16; m; m >>= 1) s += __shfl_xor(s, m);
    inv = frcp(s);
  }
  __syncthreads();

  // ---- P3: wv[c] = (sum_j a_j y2[j][c]) / s ----
  {
    float w = 0.f;
    for (int jj = half; jj < nj; jj += 2) w = fmaf(es[il][jj], y2s[jb + jj][c16], w);
    w += __shfl_xor(w, 16);
    if (half == 0) zs[il][c16] = w * inv;
  }
  __syncthreads();

  // ---- P4: attn = wv@Wv ; residual ; LN1 ----
  float yln;
  {
    float a = 0.f;
#pragma unroll
    for (int c = 0; c < C_; ++c) a = fmaf(zs[il][c], Wvs[c][c16], a);
    float y0 = y1s[il][c16] + a;
    float s1 = y0, s2 = y0 * y0;
#pragma unroll
    for (int m = 8; m; m >>= 1) { s1 += __shfl_xor(s1, m); s2 += __shfl_xor(s2, m); }
    float mean = s1 * (1.f / 16.f);
    float var  = s2 * (1.f / 16.f) - mean * mean;
    float rstd = rsqrtf(fmaxf(var, 0.f) + 1e-14f);
    yln = (y0 - mean) * rstd * g1s[c16] + be1s[c16];
    if (half == 0) ya[il][c16] = yln;
  }
  __syncthreads();

  // ---- P5: FF hidden ----
#pragma unroll
  for (int t = 0; t < 4; ++t) {
    int u = sub + 32 * t;
    float a = b1s[u];
#pragma unroll
    for (int c = 0; c < C_; ++c) a = fmaf(ya[il][c], W1s[c][u], a);
    es[il][u] = fmaxf(a, 0.f);
  }
  __syncthreads();

  // ---- P6: FF out + residual + LN2 -> zs[i][c] ----
  {
    float o = 0.f;
    int u0 = half * 64;
#pragma unroll
    for (int uu = 0; uu < 64; ++uu) o = fmaf(es[il][u0 + uu], W2s[u0 + uu][c16], o);
    o += __shfl_xor(o, 16);
    float y0 = yln + o + b2s[c16];
    float s1 = y0, s2 = y0 * y0;
#pragma unroll
    for (int m = 8; m; m >>= 1) { s1 += __shfl_xor(s1, m); s2 += __shfl_xor(s2, m); }
    float mean = s1 * (1.f / 16.f);
    float var  = s2 * (1.f / 16.f) - mean * mean;
    float rstd = rsqrtf(fmaxf(var, 0.f) + 1e-14f);
    if (half == 0) zs[il][c16] = (y0 - mean) * rstd * g2s[c16] + be2s[c16];
  }
  __syncthreads();

  // ---- P7: transposed coalesced fp32 store [B][C][L] ----
  if (tid < C_ * TI2) {
    int c = tid >> 3, i = tid & 7;
    out[(b * C_ + c) * L_ + i0 + i] = zs[i][c];
  }
}

extern "C" void kernel_launch(void* const* d_in, const int* in_sizes, int n_in,
                              void* d_out, int out_size, void* d_ws, size_t ws_size,
                              hipStream_t stream) {
  (void)in_sizes; (void)n_in; (void)out_size; (void)ws_size;
  const float* const* in = reinterpret_cast<const float* const*>(d_in);
  float* y1w = reinterpret_cast<float*>(d_ws);
  float* y2w = y1w + 4 * L_ * C_;

  BranchP Pa { in[0],  in[2],  in[3],  in[4],  in[5],  in[6],  in[7],
               in[8],  in[9],  in[10], in[11], in[12], in[13], in[14], y1w };
  BranchP Pb { in[1],  in[15], in[16], in[17], in[18], in[19], in[20],
               in[21], in[22], in[23], in[24], in[25], in[26], in[27], y2w };

  branch_kernel<<<dim3(L_ / TI1, 4, 2), 256, 0, stream>>>(Pa, Pb);
  cross_kernel<<<dim3(L_ / TI2, 4), 256, 0, stream>>>(
      y1w, y2w, in[28], in[29], in[30],
      in[31], in[32], in[33], in[34], in[35], in[36], in[37], in[38],
      reinterpret_cast<float*>(d_out));
}

// Round 9
// 169.627 us; speedup vs baseline: 1.0157x; 1.0157x over previous
//
#include <hip/hip_runtime.h>

// All I/O fp32. dur_us budget (measured r8): ~40us harness ws-poison fill
// (256MiB @ 6.8TB/s, untouchable) + ~80us restore-dispatch overhead +
// ~50us kernels (the only controllable term).

#define L_    1024
#define C_    16
#define US_   32
#define HID_  128
#define TI1   8
#define TI2   4
#define K2    2.885390082f   // 2*log2(e)
#define L2E   1.442695041f   // log2(e)

__device__ __forceinline__ float frcp(float x)  { return __builtin_amdgcn_rcpf(x); }
__device__ __forceinline__ float fexp2(float x) { return __builtin_amdgcn_exp2f(x); }

struct BranchP {
  const float *x, *Wt, *Wx, *bh, *Wa, *ba, *g1, *be1, *W1, *b1, *W2, *b2, *g2, *be2;
  float* y;   // out: [4][1024][16] fp32, position-major
};

// One block: (branch, batch, 8-row i-tile). Self-attn(band) + LN + FF + LN.
// Scores bounded (|e-ba| <= sum|Wa| ~ 0.64) => max-free softmax, exp2-folded.
__global__ __launch_bounds__(256) void branch_kernel(BranchP Pa, BranchP Pb) {
  const BranchP P = blockIdx.z ? Pb : Pa;
  const int b   = blockIdx.y;
  const int i0  = blockIdx.x * TI1;
  const int tid = threadIdx.x;
  const int j0  = max(0, i0 - 63);
  const int j1  = min(L_, i0 + TI1 + 64);
  const int Wd  = j1 - j0;               // <= 135

  __shared__ float xs[C_][137];          // x[c][j-j0]
  __shared__ union {
    struct { float ks[136][33]; float qs[TI1][33]; } a;                       // P1-P2
    struct { float W1s[C_][129]; float W2s[HID_][17]; float b1s[HID_]; } bb;  // P3+
  } ovl;
  __shared__ float es[TI1][129];         // exp(score) numerators
  __shared__ float ya[TI1][17];
  __shared__ float Wts[C_][US_], Wxs[C_][US_];   // pre-scaled by K2
  __shared__ float m2was[US_], bhs[US_];         // -K2*Wa ; K2*bh
  __shared__ float g1s[C_], be1s[C_], b2s[C_], g2s[C_], be2s[C_];
  __shared__ float bas;

  // ---- register prefetch of FF weights (consumed at P3) ----
  float w1r[8], w2r[8], b1r = 0.f;
#pragma unroll
  for (int t = 0; t < 8; ++t) { w1r[t] = P.W1[tid + 256 * t]; w2r[t] = P.W2[tid + 256 * t]; }
  if (tid < HID_) b1r = P.b1[tid];

  // ---- P0: weights + x slice ----
  for (int idx = tid; idx < C_ * US_; idx += 256) {
    int c = idx >> 5, u = idx & 31;
    Wts[c][u] = K2 * P.Wt[idx];
    Wxs[c][u] = K2 * P.Wx[idx];
  }
  if (tid < US_) { m2was[tid] = -K2 * P.Wa[tid]; bhs[tid] = K2 * P.bh[tid]; }
  if (tid < C_) {
    g1s[tid] = P.g1[tid]; be1s[tid] = P.be1[tid];
    g2s[tid] = P.g2[tid]; be2s[tid] = P.be2[tid];
    b2s[tid] = P.b2[tid];
  }
  if (tid == 0) bas = P.ba[0];
  for (int idx = tid; idx < C_ * Wd; idx += 256) {
    int c = idx / Wd, jj = idx - c * Wd;
    xs[c][jj] = P.x[(b * C_ + c) * L_ + j0 + jj];
  }
  __syncthreads();

  // ---- P1: k = K2*(x@Wx + bh), q = K2*(x@Wt) ----
  for (int idx = tid; idx < Wd * US_; idx += 256) {
    int j = idx >> 5, u = idx & 31;
    float a = bhs[u];
#pragma unroll
    for (int c = 0; c < C_; ++c) a = fmaf(xs[c][j], Wxs[c][u], a);
    ovl.a.ks[j][u] = a;
  }
  {
    int i = tid >> 5, u = tid & 31;    // exactly 256 = 8*32
    float a = 0.f;
#pragma unroll
    for (int c = 0; c < C_; ++c) a = fmaf(xs[c][i0 - j0 + i], Wts[c][u], a);
    ovl.a.qs[i][u] = a;
  }
  __syncthreads();

  const int il   = tid >> 5;            // row 0..7 (32 lanes/row)
  const int sub  = tid & 31;
  const int ig   = i0 + il;
  const int jlo  = max(0, ig - 63), jhi = min(L_, ig + 65);
  const int nj   = jhi - jlo;           // 64..128
  const int jb   = jlo - j0;
  const int c16  = sub & 15;
  const int half = sub >> 4;

  // ---- P2: single-pass max-free softmax, all in log2 units ----
  // e*L2E = [L2E*ba + L2E*sum(Wa)] + sum_u m2was[u]/(1+2^z) ; v = 2^(e*L2E)
  float inv;
  {
    float xq[US_];
#pragma unroll
    for (int u = 0; u < US_; ++u) xq[u] = ovl.a.qs[il][u];
    float eacc = L2E * bas;
#pragma unroll
    for (int u = 0; u < US_; ++u) eacc -= 0.5f * m2was[u];   // + L2E*sum(Wa)
    float s = 0.f;
    for (int jj = sub; jj < nj; jj += 32) {
      const float* kr = ovl.a.ks[jb + jj];
      float acc = eacc;
#pragma unroll
      for (int u = 0; u < US_; ++u) {
        float t = fexp2(xq[u] + kr[u]);
        acc = fmaf(m2was[u], frcp(1.0f + t), acc);
      }
      float v = fexp2(acc);
      es[il][jj] = v;
      s += v;
    }
#pragma unroll
    for (int m = 16; m; m >>= 1) s += __shfl_xor(s, m);
    inv = frcp(s + 1e-5f);
  }
  __syncthreads();

  // ---- P3: FF weights regs->LDS (dead union); v = a@x ; residual ; LN1 ----
#pragma unroll
  for (int t = 0; t < 8; ++t) {
    int idx = tid + 256 * t;
    ovl.bb.W1s[idx >> 7][idx & 127] = w1r[t];
  }
#pragma unroll
  for (int t = 0; t < 8; ++t) {
    int idx = tid + 256 * t;
    ovl.bb.W2s[idx >> 4][idx & 15] = w2r[t];
  }
  if (tid < HID_) ovl.bb.b1s[tid] = b1r;
  float yln;
  {
    float v = 0.f;
    for (int jj = half; jj < nj; jj += 2) v = fmaf(es[il][jj], xs[c16][jb + jj], v);
    v += __shfl_xor(v, 16);
    float y0 = xs[c16][ig - j0] + v * inv;
    float s1 = y0, s2 = y0 * y0;
#pragma unroll
    for (int m = 8; m; m >>= 1) { s1 += __shfl_xor(s1, m); s2 += __shfl_xor(s2, m); }
    float mean = s1 * (1.f / 16.f);
    float var  = s2 * (1.f / 16.f) - mean * mean;
    float rstd = rsqrtf(fmaxf(var, 0.f) + 1e-14f);
    yln = (y0 - mean) * rstd * g1s[c16] + be1s[c16];
    if (half == 0) ya[il][c16] = yln;
  }
  __syncthreads();

  // ---- P4: h = relu(y@W1 + b1) ----
#pragma unroll
  for (int t = 0; t < 4; ++t) {
    int u = sub + 32 * t;
    float a = ovl.bb.b1s[u];
#pragma unroll
    for (int c = 0; c < C_; ++c) a = fmaf(ya[il][c], ovl.bb.W1s[c][u], a);
    es[il][u] = fmaxf(a, 0.f);
  }
  __syncthreads();

  // ---- P5: FF out + residual + LN2 -> fp32 y [b][i][c] ----
  {
    float o = 0.f;
    int u0 = half * 64;
#pragma unroll
    for (int uu = 0; uu < 64; ++uu) o = fmaf(es[il][u0 + uu], ovl.bb.W2s[u0 + uu][c16], o);
    o += __shfl_xor(o, 16);
    float y0 = yln + o + b2s[c16];
    float s1 = y0, s2 = y0 * y0;
#pragma unroll
    for (int m = 8; m; m >>= 1) { s1 += __shfl_xor(s1, m); s2 += __shfl_xor(s2, m); }
    float mean = s1 * (1.f / 16.f);
    float var  = s2 * (1.f / 16.f) - mean * mean;
    float rstd = rsqrtf(fmaxf(var, 0.f) + 1e-14f);
    if (half == 0)
      P.y[(b * L_ + ig) * C_ + c16] = (y0 - mean) * rstd * g2s[c16] + be2s[c16];
  }
}

// Cross-attn, M = 0.25*L2E*Wq*Wk^T fused; max-free softmax (|score|<~0.5);
// TI2=4: one wave per row, 1024 blocks (4/CU).
__global__ __launch_bounds__(256) void cross_kernel(
    const float* __restrict__ y1g, const float* __restrict__ y2g,
    const float* Wq, const float* Wk, const float* Wv,
    const float* g1, const float* be1, const float* W1, const float* b1,
    const float* W2, const float* b2, const float* g2, const float* be2,
    float* out) {
  const int b   = blockIdx.y;
  const int i0  = blockIdx.x * TI2;
  const int tid = threadIdx.x;
  const int j0  = max(0, i0 - 63);
  const int j1  = min(L_, i0 + TI2 + 64);
  const int Wd  = j1 - j0;               // <= 131

  __shared__ float y1s[TI2][17];
  __shared__ float y2s[132][17];
  __shared__ float Ms[C_][17];
  __shared__ float zs[TI2][17];          // z ; reused as wv ; reused as out
  __shared__ float es[TI2][129];
  __shared__ float ya[TI2][17];
  __shared__ float Wqs[C_][C_], Wks[C_][C_], Wvs[C_][C_];
  __shared__ float W1s[C_][129], W2s[HID_][17], b1s[HID_];
  __shared__ float g1s[C_], be1s[C_], b2s[C_], g2s[C_], be2s[C_];

  // ---- P0 ----
  {
    int c = tid >> 4, u = tid & 15;
    Wqs[c][u] = Wq[tid]; Wks[c][u] = Wk[tid]; Wvs[c][u] = Wv[tid];
  }
  if (tid < TI2 * C_)
    y1s[tid >> 4][tid & 15] = y1g[(b * L_ + i0 + (tid >> 4)) * C_ + (tid & 15)];
  for (int idx = tid; idx < C_ * HID_; idx += 256) {
    W1s[idx >> 7][idx & 127] = W1[idx];
    W2s[idx >> 4][idx & 15]  = W2[idx];
  }
  if (tid < HID_) b1s[tid] = b1[tid];
  if (tid < C_) {
    g1s[tid] = g1[tid]; be1s[tid] = be1[tid];
    g2s[tid] = g2[tid]; be2s[tid] = be2[tid];
    b2s[tid] = b2[tid];
  }
  for (int idx = tid; idx < Wd * C_; idx += 256) {
    int jj = idx >> 4, c = idx & 15;
    y2s[jj][c] = y2g[(b * L_ + j0 + jj) * C_ + c];
  }
  __syncthreads();

  // ---- P1a: M = 0.25*L2E * Wq Wk^T (log2-folded) ----
  {
    int c1 = tid >> 4, c2 = tid & 15;
    float m = 0.f;
#pragma unroll
    for (int u = 0; u < C_; ++u) m = fmaf(Wqs[c1][u], Wks[c2][u], m);
    Ms[c1][c2] = (0.25f * L2E) * m;
  }
  __syncthreads();
  // ---- P1b: z[i][c] = sum_c' y1[i][c'] M[c'][c] ----
  if (tid < TI2 * C_) {
    int i = tid >> 4, c = tid & 15;
    float z = 0.f;
#pragma unroll
    for (int cc = 0; cc < C_; ++cc) z = fmaf(y1s[i][cc], Ms[cc][c], z);
    zs[i][c] = z;
  }
  __syncthreads();

  const int il   = tid >> 6;            // row 0..3, one full wave per row
  const int sub  = tid & 63;
  const int ig   = i0 + il;
  const int jlo  = max(0, ig - 63), jhi = min(L_, ig + 65);
  const int nj   = jhi - jlo;           // 64..128
  const int jb   = jlo - j0;
  const int c16  = sub & 15;
  const int quad = sub >> 4;            // 0..3

  // ---- P2: max-free scores: v = 2^(z.y2) ; sum ----
  float inv;
  {
    float zr[C_];
#pragma unroll
    for (int c = 0; c < C_; ++c) zr[c] = zs[il][c];
    float s = 0.f;
    for (int jj = sub; jj < nj; jj += 64) {
      const float* yr = y2s[jb + jj];
      float a = 0.f;
#pragma unroll
      for (int c = 0; c < C_; ++c) a = fmaf(zr[c], yr[c], a);
      float v = fexp2(a);
      es[il][jj] = v;
      s += v;
    }
#pragma unroll
    for (int m = 32; m; m >>= 1) s += __shfl_xor(s, m);
    inv = frcp(s);
  }
  __syncthreads();

  // ---- P3: wv[c] = (sum_j a_j y2[j][c]) / s ----
  {
    float w = 0.f;
    for (int jj = quad; jj < nj; jj += 4) w = fmaf(es[il][jj], y2s[jb + jj][c16], w);
    w += __shfl_xor(w, 16);
    w += __shfl_xor(w, 32);
    if (quad == 0) zs[il][c16] = w * inv;
  }
  __syncthreads();

  // ---- P4: attn = wv@Wv ; residual ; LN1 ----
  float yln;
  {
    float a = 0.f;
#pragma unroll
    for (int c = 0; c < C_; ++c) a = fmaf(zs[il][c], Wvs[c][c16], a);
    float y0 = y1s[il][c16] + a;
    float s1 = y0, s2 = y0 * y0;
#pragma unroll
    for (int m = 8; m; m >>= 1) { s1 += __shfl_xor(s1, m); s2 += __shfl_xor(s2, m); }
    float mean = s1 * (1.f / 16.f);
    float var  = s2 * (1.f / 16.f) - mean * mean;
    float rstd = rsqrtf(fmaxf(var, 0.f) + 1e-14f);
    yln = (y0 - mean) * rstd * g1s[c16] + be1s[c16];
    if (quad == 0) ya[il][c16] = yln;
  }
  __syncthreads();

  // ---- P5: FF hidden ----
#pragma unroll
  for (int t = 0; t < 2; ++t) {
    int u = sub + 64 * t;
    float a = b1s[u];
#pragma unroll
    for (int c = 0; c < C_; ++c) a = fmaf(ya[il][c], W1s[c][u], a);
    es[il][u] = fmaxf(a, 0.f);
  }
  __syncthreads();

  // ---- P6: FF out + residual + LN2 -> zs[i][c] ----
  {
    float o = 0.f;
    int u0 = quad * 32;
#pragma unroll
    for (int uu = 0; uu < 32; ++uu) o = fmaf(es[il][u0 + uu], W2s[u0 + uu][c16], o);
    o += __shfl_xor(o, 16);
    o += __shfl_xor(o, 32);
    float y0 = yln + o + b2s[c16];
    float s1 = y0, s2 = y0 * y0;
#pragma unroll
    for (int m = 8; m; m >>= 1) { s1 += __shfl_xor(s1, m); s2 += __shfl_xor(s2, m); }
    float mean = s1 * (1.f / 16.f);
    float var  = s2 * (1.f / 16.f) - mean * mean;
    float rstd = rsqrtf(fmaxf(var, 0.f) + 1e-14f);
    if (quad == 0) zs[il][c16] = (y0 - mean) * rstd * g2s[c16] + be2s[c16];
  }
  __syncthreads();

  // ---- P7: transposed fp32 store [B][C][L] ----
  if (tid < C_ * TI2) {
    int c = tid >> 2, i = tid & 3;
    out[(b * C_ + c) * L_ + i0 + i] = zs[i][c];
  }
}

extern "C" void kernel_launch(void* const* d_in, const int* in_sizes, int n_in,
                              void* d_out, int out_size, void* d_ws, size_t ws_size,
                              hipStream_t stream) {
  (void)in_sizes; (void)n_in; (void)out_size; (void)ws_size;
  const float* const* in = reinterpret_cast<const float* const*>(d_in);
  float* y1w = reinterpret_cast<float*>(d_ws);
  float* y2w = y1w + 4 * L_ * C_;

  BranchP Pa { in[0],  in[2],  in[3],  in[4],  in[5],  in[6],  in[7],
               in[8],  in[9],  in[10], in[11], in[12], in[13], in[14], y1w };
  BranchP Pb { in[1],  in[15], in[16], in[17], in[18], in[19], in[20],
               in[21], in[22], in[23], in[24], in[25], in[26], in[27], y2w };

  branch_kernel<<<dim3(L_ / TI1, 4, 2), 256, 0, stream>>>(Pa, Pb);
  cross_kernel<<<dim3(L_ / TI2, 4), 256, 0, stream>>>(
      y1w, y2w, in[28], in[29], in[30],
      in[31], in[32], in[33], in[34], in[35], in[36], in[37], in[38],
      reinterpret_cast<float*>(d_out));
}

// Round 10
// 168.463 us; speedup vs baseline: 1.0228x; 1.0069x over previous
//
#include <hip/hip_runtime.h>

// All I/O fp32. Measured budget (r8/r9): ~40us ws-poison fill (256MiB @ 85%
// HBM peak, untouchable) + ~110us restore-dispatch overhead + kernels.

#define L_    1024
#define C_    16
#define US_   32
#define HID_  128
#define TI1   8
#define TI2   4
#define K2    2.885390082f   // 2*log2(e)
#define L2E   1.442695041f   // log2(e)

__device__ __forceinline__ float frcp(float x)  { return __builtin_amdgcn_rcpf(x); }
__device__ __forceinline__ float fexp2(float x) { return __builtin_amdgcn_exp2f(x); }

// ---- kq_kernel: k = K2*(x@Wx + bh), q = K2*(x@Wt) for all (br,b,j,u). ----
// Removes the 17x redundant per-block halo recompute and the 18KB ks LDS.
__global__ __launch_bounds__(256) void kq_kernel(
    const float* __restrict__ x1, const float* __restrict__ x2,
    const float* __restrict__ Wt1, const float* __restrict__ Wx1, const float* __restrict__ bh1,
    const float* __restrict__ Wt2, const float* __restrict__ Wx2, const float* __restrict__ bh2,
    float* __restrict__ kw, float* __restrict__ qw) {
  const int idx = blockIdx.x * 256 + threadIdx.x;   // = ((br*4+b)*1024 + j)*32 + u
  const int u  = idx & 31;
  const int j  = (idx >> 5) & 1023;
  const int b  = (idx >> 15) & 3;
  const int br = idx >> 17;
  const float* x  = br ? x2 : x1;
  const float* Wt = br ? Wt2 : Wt1;
  const float* Wx = br ? Wx2 : Wx1;
  const float* bh = br ? bh2 : bh1;
  float ka = bh[u];
  float qa = 0.f;
#pragma unroll
  for (int c = 0; c < C_; ++c) {
    float xv = x[(b * C_ + c) * L_ + j];
    ka = fmaf(xv, Wx[c * US_ + u], ka);
    qa = fmaf(xv, Wt[c * US_ + u], qa);
  }
  kw[idx] = K2 * ka;
  qw[idx] = K2 * qa;
}

struct BranchP {
  const float *x, *Wa, *ba, *g1, *be1, *W1, *b1, *W2, *b2, *g2, *be2;
  float* y;   // out: [4][1024][16] fp32, position-major
};

// One block: (branch, batch, 8-row i-tile). Band attn + LN + FF + LN.
// k/q precomputed (global, L2-hot); W1/W2 read direct from global (L2-hot).
// LDS ~15KB -> high blocks/CU.
__global__ __launch_bounds__(256) void branch_kernel(BranchP Pa, BranchP Pb,
    const float* __restrict__ kw, const float* __restrict__ qw) {
  const int br  = blockIdx.z;
  const BranchP P = br ? Pb : Pa;
  const int b   = blockIdx.y;
  const int i0  = blockIdx.x * TI1;
  const int tid = threadIdx.x;
  const int j0  = max(0, i0 - 63);
  const int j1  = min(L_, i0 + TI1 + 64);
  const int Wd  = j1 - j0;               // <= 135

  __shared__ float xs[C_][137];
  __shared__ float qs[TI1][33];
  __shared__ float es[TI1][129];
  __shared__ float ya[TI1][17];
  __shared__ float m2was[US_];           // -K2*Wa
  __shared__ float b1s[HID_];
  __shared__ float g1s[C_], be1s[C_], b2s[C_], g2s[C_], be2s[C_];
  __shared__ float bas;

  // ---- P0: q rows + x slice + small params ----
  {
    int row = tid >> 5, u = tid & 31;    // 256 = 8*32 exactly
    qs[row][u] = qw[(((br * 4 + b) << 10) + i0 + row) * US_ + u];
  }
  if (tid < US_) m2was[tid] = -K2 * P.Wa[tid];
  if (tid < HID_) b1s[tid] = P.b1[tid];
  if (tid < C_) {
    g1s[tid] = P.g1[tid]; be1s[tid] = P.be1[tid];
    g2s[tid] = P.g2[tid]; be2s[tid] = P.be2[tid];
    b2s[tid] = P.b2[tid];
  }
  if (tid == 0) bas = P.ba[0];
  for (int idx = tid; idx < C_ * Wd; idx += 256) {
    int c = idx / Wd, jj = idx - c * Wd;
    xs[c][jj] = P.x[(b * C_ + c) * L_ + j0 + jj];
  }
  __syncthreads();

  const int il   = tid >> 5;            // row 0..7 (32 lanes/row)
  const int sub  = tid & 31;
  const int ig   = i0 + il;
  const int jlo  = max(0, ig - 63), jhi = min(L_, ig + 65);
  const int nj   = jhi - jlo;           // 64..128
  const int jb   = jlo - j0;
  const int c16  = sub & 15;
  const int half = sub >> 4;

  // ---- P2: max-free softmax in log2 units (|e-ba| <= sum|Wa|, bounded) ----
  float inv;
  {
    float eacc = L2E * bas;
#pragma unroll
    for (int u = 0; u < US_; ++u) eacc -= 0.5f * m2was[u];   // + L2E*sum(Wa)
    const float4* kbase =
        reinterpret_cast<const float4*>(kw + ((((br * 4 + b) << 10) + jlo) * US_));
    float s = 0.f;
    for (int jj = sub; jj < nj; jj += 32) {
      const float4* kr = kbase + jj * 8;
      float acc = eacc;
#pragma unroll
      for (int t = 0; t < 8; ++t) {
        float4 kv = kr[t];
        acc = fmaf(m2was[4*t+0], frcp(1.f + fexp2(qs[il][4*t+0] + kv.x)), acc);
        acc = fmaf(m2was[4*t+1], frcp(1.f + fexp2(qs[il][4*t+1] + kv.y)), acc);
        acc = fmaf(m2was[4*t+2], frcp(1.f + fexp2(qs[il][4*t+2] + kv.z)), acc);
        acc = fmaf(m2was[4*t+3], frcp(1.f + fexp2(qs[il][4*t+3] + kv.w)), acc);
      }
      float v = fexp2(acc);
      es[il][jj] = v;
      s += v;
    }
#pragma unroll
    for (int m = 16; m; m >>= 1) s += __shfl_xor(s, m);
    inv = frcp(s + 1e-5f);
  }
  __syncthreads();

  // ---- P3: v = a@x ; residual ; LN1 ----
  float yln;
  {
    float v = 0.f;
    for (int jj = half; jj < nj; jj += 2) v = fmaf(es[il][jj], xs[c16][jb + jj], v);
    v += __shfl_xor(v, 16);
    float y0 = xs[c16][ig - j0] + v * inv;
    float s1 = y0, s2 = y0 * y0;
#pragma unroll
    for (int m = 8; m; m >>= 1) { s1 += __shfl_xor(s1, m); s2 += __shfl_xor(s2, m); }
    float mean = s1 * (1.f / 16.f);
    float var  = s2 * (1.f / 16.f) - mean * mean;
    float rstd = rsqrtf(fmaxf(var, 0.f) + 1e-14f);
    yln = (y0 - mean) * rstd * g1s[c16] + be1s[c16];
    if (half == 0) ya[il][c16] = yln;
  }
  __syncthreads();

  // ---- P4: h = relu(y@W1 + b1), W1 direct from global (L2-hot) ----
#pragma unroll
  for (int t = 0; t < 4; ++t) {
    int u = sub + 32 * t;
    float a = b1s[u];
#pragma unroll
    for (int c = 0; c < C_; ++c) a = fmaf(ya[il][c], P.W1[c * HID_ + u], a);
    es[il][u] = fmaxf(a, 0.f);
  }
  __syncthreads();

  // ---- P5: FF out + residual + LN2 -> fp32 y [b][i][c] ----
  {
    float o = 0.f;
    int u0 = half * 64;
#pragma unroll
    for (int uu = 0; uu < 64; ++uu)
      o = fmaf(es[il][u0 + uu], P.W2[(u0 + uu) * C_ + c16], o);
    o += __shfl_xor(o, 16);
    float y0 = yln + o + b2s[c16];
    float s1 = y0, s2 = y0 * y0;
#pragma unroll
    for (int m = 8; m; m >>= 1) { s1 += __shfl_xor(s1, m); s2 += __shfl_xor(s2, m); }
    float mean = s1 * (1.f / 16.f);
    float var  = s2 * (1.f / 16.f) - mean * mean;
    float rstd = rsqrtf(fmaxf(var, 0.f) + 1e-14f);
    if (half == 0)
      P.y[(b * L_ + ig) * C_ + c16] = (y0 - mean) * rstd * g2s[c16] + be2s[c16];
  }
}

// Cross-attn, M = 0.25*L2E*Wq*Wk^T fused; max-free softmax; one wave per row.
// W1/W2 direct from global; LDS ~17KB.
__global__ __launch_bounds__(256) void cross_kernel(
    const float* __restrict__ y1g, const float* __restrict__ y2g,
    const float* Wq, const float* Wk, const float* Wv,
    const float* g1, const float* be1, const float* __restrict__ W1, const float* b1,
    const float* __restrict__ W2, const float* b2, const float* g2, const float* be2,
    float* out) {
  const int b   = blockIdx.y;
  const int i0  = blockIdx.x * TI2;
  const int tid = threadIdx.x;
  const int j0  = max(0, i0 - 63);
  const int j1  = min(L_, i0 + TI2 + 64);
  const int Wd  = j1 - j0;               // <= 131

  __shared__ float y1s[TI2][17];
  __shared__ float y2s[132][17];
  __shared__ float Ms[C_][17];
  __shared__ float zs[TI2][17];          // z ; reused as wv ; reused as out
  __shared__ float es[TI2][129];
  __shared__ float ya[TI2][17];
  __shared__ float Wqs[C_][C_], Wks[C_][C_], Wvs[C_][C_];
  __shared__ float b1s[HID_];
  __shared__ float g1s[C_], be1s[C_], b2s[C_], g2s[C_], be2s[C_];

  // ---- P0 ----
  {
    int c = tid >> 4, u = tid & 15;
    Wqs[c][u] = Wq[tid]; Wks[c][u] = Wk[tid]; Wvs[c][u] = Wv[tid];
  }
  if (tid < TI2 * C_)
    y1s[tid >> 4][tid & 15] = y1g[(b * L_ + i0 + (tid >> 4)) * C_ + (tid & 15)];
  if (tid < HID_) b1s[tid] = b1[tid];
  if (tid < C_) {
    g1s[tid] = g1[tid]; be1s[tid] = be1[tid];
    g2s[tid] = g2[tid]; be2s[tid] = be2[tid];
    b2s[tid] = b2[tid];
  }
  for (int idx = tid; idx < Wd * C_; idx += 256) {
    int jj = idx >> 4, c = idx & 15;
    y2s[jj][c] = y2g[(b * L_ + j0 + jj) * C_ + c];
  }
  __syncthreads();

  // ---- P1a: M = 0.25*L2E * Wq Wk^T ----
  {
    int c1 = tid >> 4, c2 = tid & 15;
    float m = 0.f;
#pragma unroll
    for (int u = 0; u < C_; ++u) m = fmaf(Wqs[c1][u], Wks[c2][u], m);
    Ms[c1][c2] = (0.25f * L2E) * m;
  }
  __syncthreads();
  // ---- P1b: z[i][c] = sum_c' y1[i][c'] M[c'][c] ----
  if (tid < TI2 * C_) {
    int i = tid >> 4, c = tid & 15;
    float z = 0.f;
#pragma unroll
    for (int cc = 0; cc < C_; ++cc) z = fmaf(y1s[i][cc], Ms[cc][c], z);
    zs[i][c] = z;
  }
  __syncthreads();

  const int il   = tid >> 6;            // row 0..3, one wave per row
  const int sub  = tid & 63;
  const int ig   = i0 + il;
  const int jlo  = max(0, ig - 63), jhi = min(L_, ig + 65);
  const int nj   = jhi - jlo;
  const int jb   = jlo - j0;
  const int c16  = sub & 15;
  const int quad = sub >> 4;

  // ---- P2: max-free scores v = 2^(z.y2) ; sum ----
  float inv;
  {
    float zr[C_];
#pragma unroll
    for (int c = 0; c < C_; ++c) zr[c] = zs[il][c];
    float s = 0.f;
    for (int jj = sub; jj < nj; jj += 64) {
      const float* yr = y2s[jb + jj];
      float a = 0.f;
#pragma unroll
      for (int c = 0; c < C_; ++c) a = fmaf(zr[c], yr[c], a);
      float v = fexp2(a);
      es[il][jj] = v;
      s += v;
    }
#pragma unroll
    for (int m = 32; m; m >>= 1) s += __shfl_xor(s, m);
    inv = frcp(s);
  }
  __syncthreads();

  // ---- P3: wv[c] = (sum_j a_j y2[j][c]) / s ----
  {
    float w = 0.f;
    for (int jj = quad; jj < nj; jj += 4) w = fmaf(es[il][jj], y2s[jb + jj][c16], w);
    w += __shfl_xor(w, 16);
    w += __shfl_xor(w, 32);
    if (quad == 0) zs[il][c16] = w * inv;
  }
  __syncthreads();

  // ---- P4: attn = wv@Wv ; residual ; LN1 ----
  float yln;
  {
    float a = 0.f;
#pragma unroll
    for (int c = 0; c < C_; ++c) a = fmaf(zs[il][c], Wvs[c][c16], a);
    float y0 = y1s[il][c16] + a;
    float s1 = y0, s2 = y0 * y0;
#pragma unroll
    for (int m = 8; m; m >>= 1) { s1 += __shfl_xor(s1, m); s2 += __shfl_xor(s2, m); }
    float mean = s1 * (1.f / 16.f);
    float var  = s2 * (1.f / 16.f) - mean * mean;
    float rstd = rsqrtf(fmaxf(var, 0.f) + 1e-14f);
    yln = (y0 - mean) * rstd * g1s[c16] + be1s[c16];
    if (quad == 0) ya[il][c16] = yln;
  }
  __syncthreads();

  // ---- P5: FF hidden, W1 direct from global ----
#pragma unroll
  for (int t = 0; t < 2; ++t) {
    int u = sub + 64 * t;
    float a = b1s[u];
#pragma unroll
    for (int c = 0; c < C_; ++c) a = fmaf(ya[il][c], W1[c * HID_ + u], a);
    es[il][u] = fmaxf(a, 0.f);
  }
  __syncthreads();

  // ---- P6: FF out + residual + LN2 -> zs[i][c] ----
  {
    float o = 0.f;
    int u0 = quad * 32;
#pragma unroll
    for (int uu = 0; uu < 32; ++uu)
      o = fmaf(es[il][u0 + uu], W2[(u0 + uu) * C_ + c16], o);
    o += __shfl_xor(o, 16);
    o += __shfl_xor(o, 32);
    float y0 = yln + o + b2s[c16];
    float s1 = y0, s2 = y0 * y0;
#pragma unroll
    for (int m = 8; m; m >>= 1) { s1 += __shfl_xor(s1, m); s2 += __shfl_xor(s2, m); }
    float mean = s1 * (1.f / 16.f);
    float var  = s2 * (1.f / 16.f) - mean * mean;
    float rstd = rsqrtf(fmaxf(var, 0.f) + 1e-14f);
    if (quad == 0) zs[il][c16] = (y0 - mean) * rstd * g2s[c16] + be2s[c16];
  }
  __syncthreads();

  // ---- P7: transposed fp32 store [B][C][L] ----
  if (tid < C_ * TI2) {
    int c = tid >> 2, i = tid & 3;
    out[(b * C_ + c) * L_ + i0 + i] = zs[i][c];
  }
}

extern "C" void kernel_launch(void* const* d_in, const int* in_sizes, int n_in,
                              void* d_out, int out_size, void* d_ws, size_t ws_size,
                              hipStream_t stream) {
  (void)in_sizes; (void)n_in; (void)out_size; (void)ws_size;
  const float* const* in = reinterpret_cast<const float* const*>(d_in);
  float* y1w = reinterpret_cast<float*>(d_ws);
  float* y2w = y1w + 4 * L_ * C_;             // +256KB
  float* kw  = y2w + 4 * L_ * C_;             // 2*4*1024*32 floats (1MB)
  float* qw  = kw + 2 * 4 * L_ * US_;         // 1MB

  kq_kernel<<<1024, 256, 0, stream>>>(
      in[0], in[1], in[2], in[3], in[4], in[15], in[16], in[17], kw, qw);

  BranchP Pa { in[0],  in[5],  in[6],  in[7],  in[8],
               in[9],  in[10], in[11], in[12], in[13], in[14], y1w };
  BranchP Pb { in[1],  in[18], in[19], in[20], in[21],
               in[22], in[23], in[24], in[25], in[26], in[27], y2w };

  branch_kernel<<<dim3(L_ / TI1, 4, 2), 256, 0, stream>>>(Pa, Pb, kw, qw);
  cross_kernel<<<dim3(L_ / TI2, 4), 256, 0, stream>>>(
      y1w, y2w, in[28], in[29], in[30],
      in[31], in[32], in[33], in[34], in[35], in[36], in[37], in[38],
      reinterpret_cast<float*>(d_out));
}